// Round 7
// baseline (267.944 us; speedup 1.0000x reference)
//
#include <hip/hip_runtime.h>
#include <hip/hip_bf16.h>

#define NN 8192
#define ND 128
#define BSZ 4096
#define CTX1 32
#define SRC 4096
#define TOPK 8
#define DROPC 5

#define BM 32          // rows per big_gemm block
#define BKC 256        // K floats per row per macro-step (1KB burst per instruction)
#define NMS (NN / BKC) // 32 macro-steps

using f4 = __attribute__((ext_vector_type(4))) float;
using s4 = __attribute__((ext_vector_type(4))) short;
using bfrag = __attribute__((ext_vector_type(8))) short;

__device__ __forceinline__ short f2bf(float x) {
  __hip_bfloat16 h = __float2bfloat16(x);
  return __builtin_bit_cast(short, h);
}

// ---------------- prep: tfn, wsum, meanpara, lin_W bf16 frag-pack ----
__global__ __launch_bounds__(256) void prep_kernel(
    const float* __restrict__ trainfeature, const float* __restrict__ bsnf,
    const float* __restrict__ para, const float* __restrict__ lin_W,
    float* __restrict__ tfn, float* __restrict__ wsum,
    float* __restrict__ meanpara, short* __restrict__ linWp) {
  int blk = blockIdx.x;
  int t = threadIdx.x;
  if (blk < 2048) {                      // tfn: 4 rows per block, one wave per row
    int row = blk * 4 + (t >> 6);
    int j = t & 63;
    float x = trainfeature[(size_t)row * ND + j];
    float ss = x * x;
    #pragma unroll
    for (int o = 32; o > 0; o >>= 1) ss += __shfl_xor(ss, o);
    float nrm = sqrtf(ss) + 1e-8f;
    tfn[(size_t)row * 64 + j] = x / nrm;
  } else if (blk < 4096) {               // wsum: 2 rows per block
    int b = (blk - 2048) * 2 + (t >> 7);
    int k = t & 127;
    float s = 0.f;
    #pragma unroll
    for (int tt = 0; tt < TOPK; ++tt)
      s += para[tt] * bsnf[((size_t)b * TOPK + tt) * ND + k];
    wsum[(size_t)b * ND + k] = s * (1.0f / TOPK);
  } else if (blk == 4096) {
    if (t == 0) {
      float s = 0.f;
      for (int tt = 0; tt < TOPK; ++tt) s += para[tt];
      *meanpara = s * (1.0f / TOPK);
    }
  } else {                               // lin_W pack: blk 4097..4108 -> kt 0..11
    int kt = blk - 4097;
    #pragma unroll
    for (int q = 0; q < 16; ++q) {
      int e = t * 16 + q;
      int nt = e >> 9, lane = (e >> 3) & 63, j = e & 7;
      float v = lin_W[(size_t)(kt * 32 + (lane >> 4) * 8 + j) * 128 + nt * 16 + (lane & 15)];
      linWp[(size_t)kt * 4096 + e] = f2bf(v);
    }
  }
}

// ---------------- generic f32 GEMM body: C[M][128] = A[M][128] @ W[128][128]
// Optional f32 output Cf. Optional bf16 MFMA-fragment-packed output Xpack:
// frag (kt,nt) is 64 lanes x 8 shorts contiguous; lane l, elem j holds
// X[kt*32 + (l>>4)*8 + j][nt*16 + (l&15)].
__device__ __forceinline__ void gemm128_body(
    const float* __restrict__ A, const float* __restrict__ W,
    const float* __restrict__ bias, const float* __restrict__ bscale_ptr,
    float* __restrict__ Cf, short* __restrict__ Xpack, int row0) {
  __shared__ float Ws[128][132];
  __shared__ float As[64][128];
  int t = threadIdx.x;
  for (int i = t; i < 128 * 32; i += 256) {
    int r = i >> 5, c = (i & 31) * 4;
    *(f4*)&Ws[r][c] = *(const f4*)&W[(size_t)r * 128 + c];
  }
  for (int i = t; i < 64 * 32; i += 256) {
    int r = i >> 5, c = (i & 31) * 4;
    *(f4*)&As[r][c] = *(const f4*)&A[(size_t)(row0 + r) * 128 + c];
  }
  __syncthreads();
  int tr = (t >> 5) * 8;
  int tc = (t & 31) * 4;
  float acc[8][4];
  #pragma unroll
  for (int i = 0; i < 8; i++)
    #pragma unroll
    for (int j = 0; j < 4; j++) acc[i][j] = 0.f;
  for (int k = 0; k < 128; k++) {
    f4 w = *(const f4*)&Ws[k][tc];
    #pragma unroll
    for (int i = 0; i < 8; i++) {
      float a = As[tr + i][k];
      acc[i][0] = fmaf(a, w[0], acc[i][0]);
      acc[i][1] = fmaf(a, w[1], acc[i][1]);
      acc[i][2] = fmaf(a, w[2], acc[i][2]);
      acc[i][3] = fmaf(a, w[3], acc[i][3]);
    }
  }
  if (bias) {
    float bsc = bscale_ptr ? *bscale_ptr : 1.0f;
    #pragma unroll
    for (int i = 0; i < 8; i++)
      #pragma unroll
      for (int j = 0; j < 4; j++) acc[i][j] += bias[tc + j] * bsc;
  }
  if (Cf) {
    #pragma unroll
    for (int i = 0; i < 8; i++) {
      int r = row0 + tr + i;
      #pragma unroll
      for (int j = 0; j < 4; j++) Cf[(size_t)r * 128 + tc + j] = acc[i][j];
    }
  }
  if (Xpack) {
    int kb = row0 + tr;              // multiple of 8
    int kt = kb >> 5;
    int lane_hi = (kb >> 3) & 3;
    #pragma unroll
    for (int j = 0; j < 4; j++) {
      int n = tc + j;
      int ln = (n & 15) | (lane_hi << 4);
      bfrag h;
      #pragma unroll
      for (int i = 0; i < 8; i++) h[i] = f2bf(acc[i][j]);
      *(bfrag*)&Xpack[((size_t)(kt * 8 + (n >> 4)) * 64 + ln) * 8] = h;
    }
  }
}

__global__ __launch_bounds__(256) void gemm128_kernel(
    const float* __restrict__ A, const float* __restrict__ W,
    const float* __restrict__ bias, const float* __restrict__ bscale_ptr,
    float* __restrict__ Cf, short* __restrict__ Xpack) {
  gemm128_body(A, W, bias, bscale_ptr, Cf, Xpack, blockIdx.x * 64);
}

// 2 projections in one launch, writing MFMA-packed bf16
__global__ __launch_bounds__(256) void proj2_kernel(
    const float* __restrict__ A0, const float* __restrict__ W0, short* __restrict__ T0,
    const float* __restrict__ A1, const float* __restrict__ W1, short* __restrict__ T1) {
  if (blockIdx.y == 0)
    gemm128_body(A0, W0, nullptr, nullptr, nullptr, T0, blockIdx.x * 64);
  else
    gemm128_body(A1, W1, nullptr, nullptr, nullptr, T1, blockIdx.x * 64);
}

// QKV in one launch
__global__ __launch_bounds__(256) void qkv_kernel(
    const float* __restrict__ A, const float* __restrict__ Wq,
    const float* __restrict__ Wk, const float* __restrict__ Wv,
    float* __restrict__ Qa, float* __restrict__ Ka, float* __restrict__ Va) {
  const float* W = blockIdx.y == 0 ? Wq : (blockIdx.y == 1 ? Wk : Wv);
  float* C = blockIdx.y == 0 ? Qa : (blockIdx.y == 1 ? Ka : Va);
  gemm128_body(A, W, nullptr, nullptr, C, nullptr, blockIdx.x * 64);
}

// ---------------- big GEMM, per-INSTRUCTION-contiguous staging:
//  bx < 256 : emb_E[m0..m0+32]  = relu(graph rows @ XEP + gcnE_b)
//  bx >= 256: emb_gb[p0..p0+32] = relu(adj[bni[p]] @ XgP + gcn_b)
// Each staging instruction: 64 lanes read rowbase + lane*16B = one contiguous
// 1KB burst (8 cache lines). Wave w stages rows w*8..w*8+7 (8 instructions).
// Convert f32->bf16 in-register, ds_write_b64 into XOR-unit-swizzled LDS
// (unit u = byte/16, u ^= row&7), MFMA reads b128 frags conflict-free.
__global__ __launch_bounds__(256, 4) void big_gemm_kernel(
    const float* __restrict__ adj, const float* __restrict__ graphm,
    const short* __restrict__ XgP, const short* __restrict__ XEP,
    const int* __restrict__ bni,
    const float* __restrict__ gcnE_b, const float* __restrict__ gcn_b,
    float* __restrict__ emb_E, float* __restrict__ emb_gb) {
  const int bx = blockIdx.x;
  const bool isG = bx >= 256;
  const int t = threadIdx.x;
  const int lane = t & 63;
  const int w = t >> 6;

  const float* __restrict__ Am = isG ? adj : graphm;
  const short* __restrict__ Xp = isG ? XgP : XEP;
  const int m0 = (isG ? bx - 256 : bx) * BM;

  // 8 per-row base pointers; each staging load: rp[i] + ms*BKC + lane*4 floats
  const float* rp[8];
  #pragma unroll
  for (int i = 0; i < 8; ++i) {
    int gr = m0 + w * 8 + i;
    if (isG) gr = bni[gr];
    rp[i] = Am + (size_t)gr * NN + lane * 4;
  }

  __shared__ short Abuf[2][BM * BKC];   // 2 x 16KB bf16, unit-swizzled

  const int fr = lane & 15;
  const int kq = lane >> 4;
  const short* Xb = Xp + (size_t)lane * 8;

  f4 acc[2][2];
  #pragma unroll
  for (int i = 0; i < 2; ++i)
    #pragma unroll
    for (int j = 0; j < 2; ++j) acc[i][j] = (f4){0.f, 0.f, 0.f, 0.f};

  f4 ld0, ld1, ld2, ld3, ld4, ld5, ld6, ld7;
  ld0 = *(const f4*)(rp[0]); ld1 = *(const f4*)(rp[1]);
  ld2 = *(const f4*)(rp[2]); ld3 = *(const f4*)(rp[3]);
  ld4 = *(const f4*)(rp[4]); ld5 = *(const f4*)(rp[5]);
  ld6 = *(const f4*)(rp[6]); ld7 = *(const f4*)(rp[7]);

  const int usw_w = (lane >> 1);        // write unit before XOR
  const int wh = (lane & 1) * 4;        // half-unit short offset

  for (int ms = 0; ms < NMS; ++ms) {
    const int cur = ms & 1;
    short* ab_w = &Abuf[cur][0];
    // convert + swizzled b64 writes (implicit vmcnt waits land here)
    {
      #define CWR(i, reg)                                                     \
        {                                                                     \
          s4 h;                                                               \
          h[0] = f2bf(reg[0]); h[1] = f2bf(reg[1]);                           \
          h[2] = f2bf(reg[2]); h[3] = f2bf(reg[3]);                           \
          int r = w * 8 + (i);                                                \
          *(s4*)&ab_w[r * 256 + (usw_w ^ (r & 7)) * 8 + wh] = h;              \
        }
      CWR(0, ld0) CWR(1, ld1) CWR(2, ld2) CWR(3, ld3)
      CWR(4, ld4) CWR(5, ld5) CWR(6, ld6) CWR(7, ld7)
      #undef CWR
    }
    __syncthreads();
    if (ms + 1 < NMS) {                 // issue next burst AFTER the barrier
      const int o = (ms + 1) * BKC;
      ld0 = *(const f4*)(rp[0] + o); ld1 = *(const f4*)(rp[1] + o);
      ld2 = *(const f4*)(rp[2] + o); ld3 = *(const f4*)(rp[3] + o);
      ld4 = *(const f4*)(rp[4] + o); ld5 = *(const f4*)(rp[5] + o);
      ld6 = *(const f4*)(rp[6] + o); ld7 = *(const f4*)(rp[7] + o);
    }
    // compute 8 k-steps from Abuf[cur]
    const short* ab = &Abuf[cur][0];
    #pragma unroll
    for (int ks = 0; ks < 8; ++ks) {
      const int u0 = ks * 4 + kq;
      bfrag a0 = *(const bfrag*)&ab[fr * 256 + (u0 ^ (fr & 7)) * 8];
      bfrag a1 = *(const bfrag*)&ab[(16 + fr) * 256 + (u0 ^ (fr & 7)) * 8];
      const short* xq = Xb + ((size_t)(ms * 8 + ks) * 8 + 2 * w) * 512;
      bfrag b0 = *(const bfrag*)(xq);
      bfrag b1 = *(const bfrag*)(xq + 512);
      acc[0][0] = __builtin_amdgcn_mfma_f32_16x16x32_bf16(a0, b0, acc[0][0], 0, 0, 0);
      acc[0][1] = __builtin_amdgcn_mfma_f32_16x16x32_bf16(a0, b1, acc[0][1], 0, 0, 0);
      acc[1][0] = __builtin_amdgcn_mfma_f32_16x16x32_bf16(a1, b0, acc[1][0], 0, 0, 0);
      acc[1][1] = __builtin_amdgcn_mfma_f32_16x16x32_bf16(a1, b1, acc[1][1], 0, 0, 0);
    }
    // one barrier per step suffices: barrier(ms+1) orders compute(ms) before
    // the ms+2 overwrite of buf[cur].
  }

  // epilogue: bias + relu
  const float* bias = isG ? gcn_b : gcnE_b;
  float* outp = isG ? emb_gb : emb_E;
  #pragma unroll
  for (int rt = 0; rt < 2; ++rt)
    #pragma unroll
    for (int n = 0; n < 2; ++n) {
      int col = (2 * w + n) * 16 + fr;
      float bv = bias[col];
      #pragma unroll
      for (int r = 0; r < 4; ++r) {
        int row = m0 + rt * 16 + kq * 4 + r;
        outp[(size_t)row * 128 + col] = fmaxf(acc[rt][n][r] + bv, 0.f);
      }
    }
}

// ---------------- fused attention: writes femb (bf16 [BSZ][384]) ----------------
__global__ __launch_bounds__(128) void attn_kernel(
    const int* __restrict__ node_rd,
    const float* __restrict__ Qa, const float* __restrict__ Ka,
    const float* __restrict__ Va, const float* __restrict__ tfn,
    const float* __restrict__ emb_gb, const float* __restrict__ simi,
    short* __restrict__ femb_bf) {
  int b = blockIdx.x;
  int t = threadIdx.x;
  __shared__ int idx[CTX1];
  __shared__ float tf0[64];
  __shared__ float qv[128];
  __shared__ float cosv[CTX1];
  __shared__ float sc[8][CTX1];

  if (t < CTX1) idx[t] = node_rd[(size_t)b * CTX1 + t] + (t == 0 ? SRC : 0);
  __syncthreads();
  int i0 = idx[0];
  if (t < 64) tf0[t] = tfn[(size_t)i0 * 64 + t];
  qv[t] = Qa[(size_t)i0 * 128 + t];
  __syncthreads();

  {  // cos[c]: 4 lanes per context
    int c = t >> 2, q = t & 3;
    const float* tfc = tfn + (size_t)idx[c] * 64;
    float s = 0.f;
    #pragma unroll
    for (int j = 0; j < 16; j++) s += tf0[q + j * 4] * tfc[q + j * 4];
    s += __shfl_xor(s, 1);
    s += __shfl_xor(s, 2);
    if (q == 0) cosv[c] = s;
  }
  __syncthreads();

  // scores[h][c]
  for (int p = t; p < 256; p += 128) {
    int h = p >> 5, c = p & 31;
    const float* kp = Ka + (size_t)idx[c] * 128 + h * 16;
    float s = 0.f;
    #pragma unroll
    for (int d = 0; d < 16; d++) s += qv[h * 16 + d] * kp[d];
    sc[h][c] = s * 0.25f + cosv[c];
  }
  __syncthreads();

  {  // softmax over c, 16 lanes per head
    int h = t >> 4, l = t & 15;
    float s0 = sc[h][l], s1 = sc[h][l + 16];
    float m = fmaxf(s0, s1);
    #pragma unroll
    for (int o = 1; o < 16; o <<= 1) m = fmaxf(m, __shfl_xor(m, o));
    float e0 = expf(s0 - m), e1 = expf(s1 - m);
    float sum = e0 + e1;
    #pragma unroll
    for (int o = 1; o < 16; o <<= 1) sum += __shfl_xor(sum, o);
    float inv = 1.0f / sum;
    sc[h][l] = e0 * inv;
    sc[h][l + 16] = e1 * inv;
  }
  __syncthreads();

  {  // PV + elu -> femb[128..256)
    int h = t >> 4, d = t & 15;
    float o = 0.f;
    #pragma unroll 4
    for (int c = 0; c < CTX1; c++)
      o += sc[h][c] * Va[(size_t)idx[c] * 128 + h * 16 + d];
    float e = (o > 0.f) ? o : expm1f(o);
    femb_bf[(size_t)b * 384 + 128 + t] = f2bf(e);
  }
  femb_bf[(size_t)b * 384 + t] = f2bf(emb_gb[(size_t)b * 128 + t]);
  femb_bf[(size_t)b * 384 + 256 + t] = f2bf(simi[(size_t)b * 128 + t]);
}

// ---------------- final projection: result = femb(bf16) @ lin_W + lin_b ----
__global__ __launch_bounds__(64) void final_kernel(
    const short* __restrict__ femb_bf, const short* __restrict__ linWp,
    const float* __restrict__ lin_b, float* __restrict__ outr) {
  const int m0 = blockIdx.x * 16;
  const int lane = threadIdx.x;
  const int fr = lane & 15;
  const int kq = lane >> 4;
  f4 acc[8];
  #pragma unroll
  for (int i = 0; i < 8; i++) acc[i] = (f4){0.f, 0.f, 0.f, 0.f};
  #pragma unroll
  for (int kt = 0; kt < 12; ++kt) {
    bfrag a = *(const bfrag*)&femb_bf[(size_t)(m0 + fr) * 384 + kt * 32 + kq * 8];
    #pragma unroll
    for (int nt = 0; nt < 8; ++nt) {
      bfrag bb = *(const bfrag*)&linWp[(size_t)(kt * 8 + nt) * 512 + lane * 8];
      acc[nt] = __builtin_amdgcn_mfma_f32_16x16x32_bf16(a, bb, acc[nt], 0, 0, 0);
    }
  }
  #pragma unroll
  for (int nt = 0; nt < 8; ++nt) {
    int n = nt * 16 + fr;
    float bv = lin_b[n];
    #pragma unroll
    for (int r = 0; r < 4; ++r)
      outr[(size_t)(m0 + kq * 4 + r) * 128 + n] = acc[nt][r] + bv;
  }
}

// ---------------- loss ----------------
__global__ __launch_bounds__(256) void loss_kernel(
    const float* __restrict__ target, const float* __restrict__ result,
    float* __restrict__ out_loss) {
  int t = threadIdx.x;
  float s = 0.f;
  for (int b = t; b < BSZ; b += 256) {
    float d = target[(size_t)b * 128 + DROPC] - result[(size_t)b * 128 + DROPC];
    s += d * d;
  }
  #pragma unroll
  for (int o = 32; o > 0; o >>= 1) s += __shfl_xor(s, o);
  __shared__ float red[4];
  if ((t & 63) == 0) red[t >> 6] = s;
  __syncthreads();
  if (t == 0) out_loss[0] = (red[0] + red[1] + red[2] + red[3]) * (1.0f / BSZ);
}

extern "C" void kernel_launch(void* const* d_in, const int* in_sizes, int n_in,
                              void* d_out, int out_size, void* d_ws, size_t ws_size,
                              hipStream_t stream) {
  const float* adj = (const float*)d_in[0];
  const float* graphm = (const float*)d_in[1];
  const float* node_emb_gcn = (const float*)d_in[2];
  const float* trainfeature = (const float*)d_in[3];
  const float* target_emb = (const float*)d_in[4];
  const float* bsnf = (const float*)d_in[5];
  const int* batch_node_idx = (const int*)d_in[8];
  const int* node_rd = (const int*)d_in[9];
  const float* translate_W = (const float*)d_in[10];
  const float* translate_b = (const float*)d_in[11];
  const float* paraForCos = (const float*)d_in[12];
  const float* gcn_W = (const float*)d_in[13];
  const float* gcn_b = (const float*)d_in[14];
  const float* gcnE_W = (const float*)d_in[15];
  const float* gcnE_b = (const float*)d_in[16];
  const float* Wq = (const float*)d_in[17];
  const float* Wk = (const float*)d_in[18];
  const float* Wv = (const float*)d_in[19];
  const float* lin_W = (const float*)d_in[20];
  const float* lin_b = (const float*)d_in[21];

  char* ws = (char*)d_ws;
  size_t off = 0;
  auto alloc = [&](size_t bytes) {
    void* p = ws + off;
    off += (bytes + 255) & ~(size_t)255;
    return p;
  };
  short* XgP = (short*)alloc((size_t)128 * NN * 2);
  short* XEP = (short*)alloc((size_t)128 * NN * 2);
  float* tfn = (float*)alloc((size_t)NN * 64 * 4);
  float* wsum = (float*)alloc((size_t)BSZ * 128 * 4);
  float* simi = (float*)alloc((size_t)BSZ * 128 * 4);
  float* Qa = (float*)alloc((size_t)NN * 128 * 4);
  float* Ka = (float*)alloc((size_t)NN * 128 * 4);
  float* Va = (float*)alloc((size_t)NN * 128 * 4);
  float* emb_E = (float*)alloc((size_t)NN * 128 * 4);
  float* emb_gb = (float*)alloc((size_t)BSZ * 128 * 4);
  float* meanpara = (float*)alloc(256);
  short* femb_bf = (short*)alloc((size_t)BSZ * 384 * 2);
  short* linWp = (short*)alloc((size_t)12 * 4096 * 2);

  float* out_res = (float*)d_out;
  float* out_loss = out_res + (size_t)BSZ * 128;

  prep_kernel<<<4109, 256, 0, stream>>>(trainfeature, bsnf, paraForCos, lin_W,
                                        tfn, wsum, meanpara, linWp);
  proj2_kernel<<<dim3(NN / 64, 2), 256, 0, stream>>>(node_emb_gcn, gcn_W, XgP,
                                                     trainfeature, gcnE_W, XEP);
  big_gemm_kernel<<<384, 256, 0, stream>>>(adj, graphm, XgP, XEP, batch_node_idx,
                                           gcnE_b, gcn_b, emb_E, emb_gb);
  qkv_kernel<<<dim3(NN / 64, 3), 256, 0, stream>>>(emb_E, Wq, Wk, Wv, Qa, Ka, Va);
  gemm128_kernel<<<BSZ / 64, 256, 0, stream>>>(wsum, translate_W, translate_b, meanpara,
                                               simi, nullptr);
  attn_kernel<<<BSZ, 128, 0, stream>>>(node_rd, Qa, Ka, Va, tfn, emb_gb, simi, femb_bf);
  final_kernel<<<BSZ / 16, 64, 0, stream>>>(femb_bf, linWp, lin_b, out_res);
  loss_kernel<<<1, 256, 0, stream>>>(target_emb, out_res, out_loss);
}